// Round 1
// baseline (276.130 us; speedup 1.0000x reference)
//
#include <hip/hip_runtime.h>
#include <hip/hip_bf16.h>

typedef short short8 __attribute__((ext_vector_type(8)));
typedef float f32x4 __attribute__((ext_vector_type(4)));
typedef unsigned short u16;

#define SCALE_C 0.17677669529663687f
#define NB 16
#define LL 4096
#define CC 256

__device__ __forceinline__ u16 f2b(float f) {
  union { float f; unsigned int u; } v; v.f = f;
  unsigned int u = v.u;
  return (u16)((u + 0x7FFFu + ((u >> 16) & 1u)) >> 16);
}
__device__ __forceinline__ float b2f(u16 b) {
  union { unsigned int u; float f; } v; v.u = ((unsigned int)b) << 16; return v.f;
}

// ---------------- prep kernels ----------------
__global__ void prep0(const float* Wq, const float* Wk, const float* Wv, const float* Wo,
                      const float* bk, const float* bv,
                      u16* wqT, u16* wkvT, u16* woT, float* bkv) {
  int j = blockIdx.x, t = threadIdx.x;
  wqT[j * 256 + t] = f2b(Wq[t * 256 + j]);
  wkvT[j * 256 + t] = f2b(Wk[t * 256 + j]);
  wkvT[(256 + j) * 256 + t] = f2b(Wv[t * 256 + j]);
  woT[j * 256 + t] = f2b(Wo[t * 256 + j]);
  if (t == 0) { bkv[j] = bk[j]; bkv[256 + j] = bv[j]; }
}

__global__ void prep1(const float* Wt, const float* Wo, const float* bt, const float* bo,
                      float* wtloT, float* btlo) {
  __shared__ float woj[256];
  int j = blockIdx.x, c = threadIdx.x;
  woj[c] = Wo[c * 256 + j];
  __syncthreads();
  float s = 0.f;
  const float* wr = Wt + c * 256;
#pragma unroll 8
  for (int t = 0; t < 256; ++t) s += wr[t] * woj[t];
  wtloT[j * 256 + c] = s;  // = Wtlo[c][j]
  if (c == 0) {
    float b = bo[j];
    for (int t = 0; t < 256; ++t) b += bt[t] * woj[t];
    btlo[j] = b;
  }
}

__global__ void prep2(const float* pk, const float* wtloT, const u16* woT, u16* B5) {
  int n = blockIdx.x >> 8, j = blockIdx.x & 255, t = threadIdx.x;
  u16* r = B5 + ((size_t)(n * 256 + j)) * 512;
  r[t] = f2b(pk[n * 256 + t] * wtloT[j * 256 + t]);
  r[256 + t] = woT[j * 256 + t];
}

// ---------------- GEMM ----------------
// C[M=65536, N=TN*NT] = A @ B^T_prepped, 128x128 tile, 4 waves, BK=64.
#define TM 128
#define TN 128
#define TKP 72  // 64 + 8 pad (bank-conflict-free reads)

template <bool AF32, int KTILES, bool DUAL, bool OUTF>
__global__ __launch_bounds__(256) void gemm_k(
    const float* Af, const u16* Ab, int ldaA, const u16* Ab2, int ldaA2,
    const u16* B, size_t bstride_n, const float* bias,
    u16* outb, float* outf, int ldc, int NT) {
  __shared__ __align__(16) u16 As[TM][TKP];
  __shared__ __align__(16) u16 Bs[TN][TKP];
  int bid = blockIdx.x;
  int mt = bid / NT, nt = bid % NT;
  int m0 = mt * TM, n0 = nt * TN;
  int tid = threadIdx.x;
  int lane = tid & 63;
  int w = tid >> 6, wm = w >> 1, wn = w & 1;
  const int ldb = KTILES * 64;
  const u16* Bp = B + (bstride_n ? (size_t)(m0 >> 12) * bstride_n : 0);

  f32x4 acc[4][4];
#pragma unroll
  for (int i = 0; i < 4; ++i)
#pragma unroll
    for (int j = 0; j < 4; ++j) acc[i][j] = (f32x4){0.f, 0.f, 0.f, 0.f};

  for (int kt = 0; kt < KTILES; ++kt) {
    // stage A
    if constexpr (AF32) {
#pragma unroll
      for (int i = 0; i < 8; ++i) {
        int c = tid + i * 256;           // 0..2047
        int row = c >> 4, f4 = c & 15;   // 16 float4 per 64-f32 row
        const float4 v = *(const float4*)(Af + (size_t)(m0 + row) * 256 + kt * 64 + f4 * 4);
        u16* d = &As[row][f4 * 4];
        d[0] = f2b(v.x); d[1] = f2b(v.y); d[2] = f2b(v.z); d[3] = f2b(v.w);
      }
    } else {
      const u16* Asel; int ldA, ktl;
      if (DUAL && kt >= KTILES / 2) { Asel = Ab2; ldA = ldaA2; ktl = kt - KTILES / 2; }
      else { Asel = Ab; ldA = ldaA; ktl = kt; }
#pragma unroll
      for (int i = 0; i < 4; ++i) {
        int c = tid + i * 256;           // 0..1023
        int row = c >> 3, u = c & 7;
        *(short8*)&As[row][u * 8] =
            *(const short8*)(Asel + (size_t)(m0 + row) * ldA + ktl * 64 + u * 8);
      }
    }
    // stage B
#pragma unroll
    for (int i = 0; i < 4; ++i) {
      int c = tid + i * 256;
      int row = c >> 3, u = c & 7;
      *(short8*)&Bs[row][u * 8] =
          *(const short8*)(Bp + (size_t)(n0 + row) * ldb + kt * 64 + u * 8);
    }
    __syncthreads();
    // compute
    short8 af[4][2], bfr[4][2];
#pragma unroll
    for (int i = 0; i < 4; ++i)
#pragma unroll
      for (int kk = 0; kk < 2; ++kk) {
        af[i][kk] = *(const short8*)&As[wm * 64 + i * 16 + (lane & 15)][kk * 32 + (lane >> 4) * 8];
        bfr[i][kk] = *(const short8*)&Bs[wn * 64 + i * 16 + (lane & 15)][kk * 32 + (lane >> 4) * 8];
      }
#pragma unroll
    for (int kk = 0; kk < 2; ++kk)
#pragma unroll
      for (int i = 0; i < 4; ++i)
#pragma unroll
        for (int j = 0; j < 4; ++j)
          acc[i][j] = __builtin_amdgcn_mfma_f32_16x16x32_bf16(af[i][kk], bfr[j][kk], acc[i][j], 0, 0, 0);
    __syncthreads();
  }
  // epilogue
#pragma unroll
  for (int i = 0; i < 4; ++i)
#pragma unroll
    for (int j = 0; j < 4; ++j) {
      int col = n0 + wn * 64 + j * 16 + (lane & 15);
      float bb = bias[col];
#pragma unroll
      for (int e = 0; e < 4; ++e) {
        int row = m0 + wm * 64 + i * 16 + (lane >> 4) * 4 + e;
        float vv = acc[i][j][e] + bb;
        if constexpr (OUTF) outf[(size_t)row * ldc + col] = vv;
        else outb[(size_t)row * ldc + col] = f2b(vv);
      }
    }
}

// ---------------- score: s[n][h][l] = ((act ⊙ g) @ Wa + ba) * SCALE ----------------
template <bool GATE>
__global__ __launch_bounds__(256) void score_k(const u16* act, int lda, const float* gate,
                                               const float* Wa, const float* ba, float* sout) {
  __shared__ float Ws[256][8];
  __shared__ float gs[256];
  int tid = threadIdx.x;
  for (int i = tid; i < 2048; i += 256) ((float*)Ws)[i] = Wa[i];
  if (GATE) gs[tid] = gate[(blockIdx.x >> 4) * 256 + tid];
  __syncthreads();
  int wv = tid >> 6, lane = tid & 63;
  int rl = lane >> 2, qq = lane & 3;
  for (int r0 = wv * 16; r0 < 256; r0 += 64) {
    int row = blockIdx.x * 256 + r0 + rl;
    const u16* ap = act + (size_t)row * lda + qq * 64;
    float acc[8] = {0, 0, 0, 0, 0, 0, 0, 0};
#pragma unroll
    for (int ch = 0; ch < 8; ++ch) {
      short8 v = *(const short8*)(ap + ch * 8);
#pragma unroll
      for (int e = 0; e < 8; ++e) {
        int c = qq * 64 + ch * 8 + e;
        float x = b2f(((u16*)&v)[e]);
        if (GATE) x *= gs[c];
#pragma unroll
        for (int h = 0; h < 8; ++h) acc[h] += x * Ws[c][h];
      }
    }
#pragma unroll
    for (int h = 0; h < 8; ++h) {
      acc[h] += __shfl_xor(acc[h], 1);
      acc[h] += __shfl_xor(acc[h], 2);
    }
    if (qq == 0) {
      int n = row >> 12, l = row & 4095;
#pragma unroll
      for (int h = 0; h < 8; ++h)
        sout[(((size_t)n * 8 + h) << 12) + l] = (acc[h] + ba[h]) * SCALE_C;
    }
  }
}

// ---------------- softmax over L + pooled[n][h*32+d] ----------------
__global__ __launch_bounds__(256) void pool_k(const float* score, const u16* act, int lda,
                                              float* pooled) {
  __shared__ float p[4096];
  __shared__ float red[8];
  __shared__ float wsum[4][32];
  int n = blockIdx.x >> 3, h = blockIdx.x & 7;
  const float* s = score + (size_t)blockIdx.x * 4096;
  int tid = threadIdx.x;
  float v[16];
  float lmax = -3.0e38f;
#pragma unroll
  for (int i = 0; i < 16; ++i) { v[i] = s[i * 256 + tid]; lmax = fmaxf(lmax, v[i]); }
  for (int o = 32; o; o >>= 1) lmax = fmaxf(lmax, __shfl_xor(lmax, o));
  if ((tid & 63) == 0) red[tid >> 6] = lmax;
  __syncthreads();
  float m = fmaxf(fmaxf(red[0], red[1]), fmaxf(red[2], red[3]));
  float lsum = 0.f;
#pragma unroll
  for (int i = 0; i < 16; ++i) { float e = __expf(v[i] - m); p[i * 256 + tid] = e; lsum += e; }
  for (int o = 32; o; o >>= 1) lsum += __shfl_xor(lsum, o);
  if ((tid & 63) == 0) red[4 + (tid >> 6)] = lsum;
  __syncthreads();
  float inv = 1.f / (red[4] + red[5] + red[6] + red[7]);
  float acc[32];
#pragma unroll
  for (int d = 0; d < 32; ++d) acc[d] = 0.f;
  const u16* ap = act + (size_t)(n * 4096) * lda + h * 32;
  for (int it = 0; it < 16; ++it) {
    int row = it * 256 + tid;
    float wgt = p[row] * inv;
    const u16* rp = ap + (size_t)row * lda;
#pragma unroll
    for (int ch = 0; ch < 4; ++ch) {
      short8 x = *(const short8*)(rp + ch * 8);
#pragma unroll
      for (int e = 0; e < 8; ++e) acc[ch * 8 + e] += wgt * b2f(((u16*)&x)[e]);
    }
  }
#pragma unroll
  for (int d = 0; d < 32; ++d)
    for (int o = 32; o; o >>= 1) acc[d] += __shfl_xor(acc[d], o);
  __syncthreads();
  if ((tid & 63) == 0)
#pragma unroll
    for (int d = 0; d < 32; ++d) wsum[tid >> 6][d] = acc[d];
  __syncthreads();
  if (tid < 32)
    pooled[(n << 8) + h * 32 + tid] = wsum[0][tid] + wsum[1][tid] + wsum[2][tid] + wsum[3][tid];
}

// ---------------- launch ----------------
extern "C" void kernel_launch(void* const* d_in, const int* in_sizes, int n_in,
                              void* d_out, int out_size, void* d_ws, size_t ws_size,
                              hipStream_t stream) {
  const float* x_q = (const float*)d_in[0];
  const float* x_kv = (const float*)d_in[1];
  const float* Wq = (const float*)d_in[2];
  const float* bq = (const float*)d_in[3];
  const float* Wqa = (const float*)d_in[4];
  const float* bqa = (const float*)d_in[5];
  const float* Wk = (const float*)d_in[6];
  const float* bk = (const float*)d_in[7];
  const float* Wka = (const float*)d_in[8];
  const float* bka = (const float*)d_in[9];
  const float* Wv = (const float*)d_in[10];
  const float* bv = (const float*)d_in[11];
  const float* Wt = (const float*)d_in[12];
  const float* bt = (const float*)d_in[13];
  const float* Wo = (const float*)d_in[14];
  const float* bo = (const float*)d_in[15];

  char* w = (char*)d_ws;
  size_t off = 0;
  u16* q_ws = (u16*)(w + off); off += (size_t)65536 * 256 * 2;      // 32MB
  u16* kv_ws = (u16*)(w + off); off += (size_t)65536 * 512 * 2;     // 64MB
  float* qscore = (float*)(w + off); off += (size_t)16 * 8 * 4096 * 4;
  float* kscore = (float*)(w + off); off += (size_t)16 * 8 * 4096 * 4;
  float* pq = (float*)(w + off); off += 16 * 256 * 4;
  float* pk = (float*)(w + off); off += 16 * 256 * 4;
  u16* wqT = (u16*)(w + off); off += 256 * 256 * 2;
  u16* wkvT = (u16*)(w + off); off += 512 * 256 * 2;
  u16* woT = (u16*)(w + off); off += 256 * 256 * 2;
  float* wtloT = (float*)(w + off); off += 256 * 256 * 4;
  float* btlo = (float*)(w + off); off += 256 * 4;
  float* bkv = (float*)(w + off); off += 512 * 4;
  u16* B5 = (u16*)(w + off); off += (size_t)16 * 256 * 512 * 2;     // 4MB
  if (ws_size < off) return;  // workspace too small — bail rather than corrupt

  prep0<<<256, 256, 0, stream>>>(Wq, Wk, Wv, Wo, bk, bv, wqT, wkvT, woT, bkv);
  prep1<<<256, 256, 0, stream>>>(Wt, Wo, bt, bo, wtloT, btlo);

  // G1: q = x_q @ Wq + bq  -> q_ws (bf16)
  gemm_k<true, 4, false, false><<<512 * 2, 256, 0, stream>>>(
      x_q, nullptr, 0, nullptr, 0, wqT, 0, bq, q_ws, nullptr, 256, 2);
  // q-score + pool
  score_k<false><<<256, 256, 0, stream>>>(q_ws, 256, nullptr, Wqa, bqa, qscore);
  pool_k<<<128, 256, 0, stream>>>(qscore, q_ws, 256, pq);

  // G2: [k|v] = x_kv @ [Wk|Wv] + [bk|bv] -> kv_ws (bf16, [65536][512])
  gemm_k<true, 4, false, false><<<512 * 4, 256, 0, stream>>>(
      x_kv, nullptr, 0, nullptr, 0, wkvT, 0, bkv, kv_ws, nullptr, 512, 4);
  // k-score (gated by pooled_q) + pool
  score_k<true><<<256, 256, 0, stream>>>(kv_ws, 512, pq, Wka, bka, kscore);
  pool_k<<<128, 256, 0, stream>>>(kscore, kv_ws, 512, pk);

  // per-n B5 = [diag(pk) * Wtlo ; Wo]  (transposed layout [n][j][k=512])
  prep2<<<16 * 256, 256, 0, stream>>>(pk, wtloT, woT, B5);

  // G3: out = v @ B5_lo + q @ Wo + btlo  (dual-A, K=512, fp32 out)
  gemm_k<false, 8, true, true><<<512 * 2, 256, 0, stream>>>(
      nullptr, kv_ws + 256, 512, q_ws, 256, B5, (size_t)256 * 512, btlo,
      nullptr, (float*)d_out, 256, 2);
}

// Round 2
// 236.977 us; speedup vs baseline: 1.1652x; 1.1652x over previous
//
#include <hip/hip_runtime.h>
#include <hip/hip_bf16.h>

typedef short short8 __attribute__((ext_vector_type(8)));
typedef float f32x4 __attribute__((ext_vector_type(4)));
typedef unsigned short u16;

#define SCALE_C 0.17677669529663687f

__device__ __forceinline__ u16 f2b(float f) {
  union { float f; unsigned int u; } v; v.f = f;
  unsigned int u = v.u;
  return (u16)((u + 0x7FFFu + ((u >> 16) & 1u)) >> 16);
}
__device__ __forceinline__ float b2f(u16 b) {
  union { unsigned int u; float f; } v; v.u = ((unsigned int)b) << 16; return v.f;
}

// ---------------- prep kernels ----------------
__global__ void prep0(const float* Wq, const float* Wk, const float* Wv, const float* Wo,
                      const float* bk, const float* bv,
                      u16* wqT, u16* wkvT, u16* woT, float* bkv) {
  int j = blockIdx.x, t = threadIdx.x;
  wqT[j * 256 + t] = f2b(Wq[t * 256 + j]);
  wkvT[j * 256 + t] = f2b(Wk[t * 256 + j]);
  wkvT[(256 + j) * 256 + t] = f2b(Wv[t * 256 + j]);
  woT[j * 256 + t] = f2b(Wo[t * 256 + j]);
  if (t == 0) { bkv[j] = bk[j]; bkv[256 + j] = bv[j]; }
}

__global__ void prep1(const float* Wt, const float* Wo, const float* bt, const float* bo,
                      float* wtloT, float* btlo) {
  __shared__ float woj[256];
  int j = blockIdx.x, c = threadIdx.x;
  woj[c] = Wo[c * 256 + j];
  __syncthreads();
  float s = 0.f;
  const float* wr = Wt + c * 256;
#pragma unroll 8
  for (int t = 0; t < 256; ++t) s += wr[t] * woj[t];
  wtloT[j * 256 + c] = s;  // = Wtlo[c][j]
  if (c == 0) {
    float b = bo[j];
    for (int t = 0; t < 256; ++t) b += bt[t] * woj[t];
    btlo[j] = b;
  }
}

__global__ void prep2(const float* pk, const float* wtloT, const u16* woT, u16* B5) {
  int n = blockIdx.x >> 8, j = blockIdx.x & 255, t = threadIdx.x;
  u16* r = B5 + ((size_t)(n * 256 + j)) * 512;
  r[t] = f2b(pk[n * 256 + t] * wtloT[j * 256 + t]);
  r[256 + t] = woT[j * 256 + t];
}

// ---------------- GEMM (128x128 tile, 4 waves, BK=64, swizzled LDS, 1-deep prefetch) ---
// LDS layout: As [128 rows][64 bf16] with 16B-granule XOR swizzle g^(row&7); Bs follows.
__device__ __forceinline__ int swz(int row, int g) { return row * 128 + ((g ^ (row & 7)) << 4); }

template <bool AF32, int KTILES, bool DUAL, bool OUTF, int NT>
__global__ __launch_bounds__(256, 3) void gemm2(
    const float* Af, const u16* Ab, const u16* Ab2,
    const u16* B, int ldb, long bstr, const float* bias,
    u16* out0, u16* out1, float* outf) {
  __shared__ __align__(16) char smem[32768];  // As 16KB + Bs 16KB
  const int nwg = NT * 512;
  int bid = blockIdx.x;
  int logical = (bid & 7) * (nwg >> 3) + (bid >> 3);  // XCD-chunked bijection (nwg%8==0)
  int mt = logical / NT, nt = logical % NT;
  int m0 = mt * 128, n0 = nt * 128;
  int tid = threadIdx.x, lane = tid & 63, w = tid >> 6;
  int wm = w >> 1, wn = w & 1, rla = lane & 15, hi = lane >> 4;
  int r0 = tid >> 3, g = tid & 7;  // staging map: 32 rows/pass, 8 granules/row

  const u16* Bb = B + (bstr ? (long)(m0 >> 12) * bstr : 0) + (size_t)n0 * ldb;

  f32x4 acc[4][4];
#pragma unroll
  for (int i = 0; i < 4; ++i)
#pragma unroll
    for (int j = 0; j < 4; ++j) acc[i][j] = (f32x4){0.f, 0.f, 0.f, 0.f};

  f32x4 paf[4][2]; short8 pab[4]; short8 pb[4];

  auto loads = [&](int kt) {
#pragma unroll
    for (int p = 0; p < 4; ++p) {
      int r = r0 + p * 32;
      if constexpr (AF32) {
        const float* s = Af + (size_t)(m0 + r) * 256 + kt * 64 + g * 8;
        paf[p][0] = *(const f32x4*)s;
        paf[p][1] = *(const f32x4*)(s + 4);
      } else {
        const u16* As_; int ktl;
        if (DUAL && kt >= KTILES / 2) { As_ = Ab2; ktl = kt - KTILES / 2; }
        else { As_ = Ab; ktl = kt; }
        pab[p] = *(const short8*)(As_ + (size_t)(m0 + r) * 256 + ktl * 64 + g * 8);
      }
      pb[p] = *(const short8*)(Bb + (size_t)r * ldb + kt * 64 + g * 8);
    }
  };
  auto stores = [&]() {
#pragma unroll
    for (int p = 0; p < 4; ++p) {
      int r = r0 + p * 32;
      int off = swz(r, g);
      if constexpr (AF32) {
        short8 s; u16* sp = (u16*)&s;
        const float* f0 = (const float*)&paf[p][0];
        const float* f1 = (const float*)&paf[p][1];
#pragma unroll
        for (int e = 0; e < 4; ++e) { sp[e] = f2b(f0[e]); sp[4 + e] = f2b(f1[e]); }
        *(short8*)(smem + off) = s;
      } else {
        *(short8*)(smem + off) = pab[p];
      }
      *(short8*)(smem + 16384 + off) = pb[p];
    }
  };

  loads(0);
  for (int kt = 0; kt < KTILES; ++kt) {
    stores();
    __syncthreads();
    if (kt + 1 < KTILES) loads(kt + 1);  // prefetch in flight under MFMA
#pragma unroll
    for (int kk = 0; kk < 2; ++kk) {
      short8 af[4], bfr[4];
#pragma unroll
      for (int i = 0; i < 4; ++i) {
        af[i] = *(const short8*)(smem + swz(wm * 64 + i * 16 + rla, kk * 4 + hi));
        bfr[i] = *(const short8*)(smem + 16384 + swz(wn * 64 + i * 16 + rla, kk * 4 + hi));
      }
#pragma unroll
      for (int i = 0; i < 4; ++i)
#pragma unroll
        for (int j = 0; j < 4; ++j)
          acc[i][j] = __builtin_amdgcn_mfma_f32_16x16x32_bf16(af[i], bfr[j], acc[i][j], 0, 0, 0);
    }
    __syncthreads();
  }
  // epilogue
#pragma unroll
  for (int i = 0; i < 4; ++i)
#pragma unroll
    for (int j = 0; j < 4; ++j) {
      int cg = n0 + wn * 64 + j * 16 + rla;
      float bb = bias[cg];
#pragma unroll
      for (int e = 0; e < 4; ++e) {
        int row = m0 + wm * 64 + i * 16 + hi * 4 + e;
        float vv = acc[i][j][e] + bb;
        if constexpr (OUTF) {
          outf[(size_t)row * 256 + cg] = vv;
        } else {
          u16* o = (cg & 256) ? out1 : out0;
          o[(size_t)row * 256 + (cg & 255)] = f2b(vv);
        }
      }
    }
}

// ---------------- score: s[n][h][l] = ((act ⊙ g) @ Wa + ba) * SCALE ----------------
template <bool GATE>
__global__ __launch_bounds__(256) void score_k(const u16* act, int lda, const float* gate,
                                               const float* Wa, const float* ba, float* sout) {
  __shared__ float Ws[256][8];
  __shared__ float gs[256];
  int tid = threadIdx.x;
  for (int i = tid; i < 2048; i += 256) ((float*)Ws)[i] = Wa[i];
  if (GATE) gs[tid] = gate[(blockIdx.x >> 4) * 256 + tid];
  __syncthreads();
  int wv = tid >> 6, lane = tid & 63;
  int rl = lane >> 2, qq = lane & 3;
  for (int r0 = wv * 16; r0 < 256; r0 += 64) {
    int row = blockIdx.x * 256 + r0 + rl;
    const u16* ap = act + (size_t)row * lda + qq * 64;
    float acc[8] = {0, 0, 0, 0, 0, 0, 0, 0};
#pragma unroll
    for (int ch = 0; ch < 8; ++ch) {
      short8 v = *(const short8*)(ap + ch * 8);
#pragma unroll
      for (int e = 0; e < 8; ++e) {
        int c = qq * 64 + ch * 8 + e;
        float x = b2f(((u16*)&v)[e]);
        if (GATE) x *= gs[c];
#pragma unroll
        for (int h = 0; h < 8; ++h) acc[h] += x * Ws[c][h];
      }
    }
#pragma unroll
    for (int h = 0; h < 8; ++h) {
      acc[h] += __shfl_xor(acc[h], 1);
      acc[h] += __shfl_xor(acc[h], 2);
    }
    if (qq == 0) {
      int n = row >> 12, l = row & 4095;
#pragma unroll
      for (int h = 0; h < 8; ++h)
        sout[(((size_t)n * 8 + h) << 12) + l] = (acc[h] + ba[h]) * SCALE_C;
    }
  }
}

// ---------------- softmax over L + pooled[n][h*32+d] ----------------
__global__ __launch_bounds__(256) void pool_k(const float* score, const u16* act, int lda,
                                              float* pooled) {
  __shared__ float p[4096];
  __shared__ float red[8];
  __shared__ float wsum[4][32];
  int n = blockIdx.x >> 3, h = blockIdx.x & 7;
  const float* s = score + (size_t)blockIdx.x * 4096;
  int tid = threadIdx.x;
  float v[16];
  float lmax = -3.0e38f;
#pragma unroll
  for (int i = 0; i < 16; ++i) { v[i] = s[i * 256 + tid]; lmax = fmaxf(lmax, v[i]); }
  for (int o = 32; o; o >>= 1) lmax = fmaxf(lmax, __shfl_xor(lmax, o));
  if ((tid & 63) == 0) red[tid >> 6] = lmax;
  __syncthreads();
  float m = fmaxf(fmaxf(red[0], red[1]), fmaxf(red[2], red[3]));
  float lsum = 0.f;
#pragma unroll
  for (int i = 0; i < 16; ++i) { float e = __expf(v[i] - m); p[i * 256 + tid] = e; lsum += e; }
  for (int o = 32; o; o >>= 1) lsum += __shfl_xor(lsum, o);
  if ((tid & 63) == 0) red[4 + (tid >> 6)] = lsum;
  __syncthreads();
  float inv = 1.f / (red[4] + red[5] + red[6] + red[7]);
  float acc[32];
#pragma unroll
  for (int d = 0; d < 32; ++d) acc[d] = 0.f;
  const u16* ap = act + (size_t)(n * 4096) * lda + h * 32;
  for (int it = 0; it < 16; ++it) {
    int row = it * 256 + tid;
    float wgt = p[row] * inv;
    const u16* rp = ap + (size_t)row * lda;
#pragma unroll
    for (int ch = 0; ch < 4; ++ch) {
      short8 x = *(const short8*)(rp + ch * 8);
#pragma unroll
      for (int e = 0; e < 8; ++e) acc[ch * 8 + e] += wgt * b2f(((u16*)&x)[e]);
    }
  }
#pragma unroll
  for (int d = 0; d < 32; ++d)
    for (int o = 32; o; o >>= 1) acc[d] += __shfl_xor(acc[d], o);
  __syncthreads();
  if ((tid & 63) == 0)
#pragma unroll
    for (int d = 0; d < 32; ++d) wsum[tid >> 6][d] = acc[d];
  __syncthreads();
  if (tid < 32)
    pooled[(n << 8) + h * 32 + tid] = wsum[0][tid] + wsum[1][tid] + wsum[2][tid] + wsum[3][tid];
}

// ---------------- launch ----------------
extern "C" void kernel_launch(void* const* d_in, const int* in_sizes, int n_in,
                              void* d_out, int out_size, void* d_ws, size_t ws_size,
                              hipStream_t stream) {
  const float* x_q = (const float*)d_in[0];
  const float* x_kv = (const float*)d_in[1];
  const float* Wq = (const float*)d_in[2];
  const float* bq = (const float*)d_in[3];
  const float* Wqa = (const float*)d_in[4];
  const float* bqa = (const float*)d_in[5];
  const float* Wk = (const float*)d_in[6];
  const float* bk = (const float*)d_in[7];
  const float* Wka = (const float*)d_in[8];
  const float* bka = (const float*)d_in[9];
  const float* Wv = (const float*)d_in[10];
  const float* bv = (const float*)d_in[11];
  const float* Wt = (const float*)d_in[12];
  const float* bt = (const float*)d_in[13];
  const float* Wo = (const float*)d_in[14];
  const float* bo = (const float*)d_in[15];

  char* w = (char*)d_ws;
  size_t off = 0;
  u16* q_ws = (u16*)(w + off); off += (size_t)65536 * 256 * 2;   // 32MB
  u16* k_ws = (u16*)(w + off); off += (size_t)65536 * 256 * 2;   // 32MB
  u16* v_ws = (u16*)(w + off); off += (size_t)65536 * 256 * 2;   // 32MB
  float* qscore = (float*)(w + off); off += (size_t)16 * 8 * 4096 * 4;
  float* kscore = (float*)(w + off); off += (size_t)16 * 8 * 4096 * 4;
  float* pq = (float*)(w + off); off += 16 * 256 * 4;
  float* pk = (float*)(w + off); off += 16 * 256 * 4;
  u16* wqT = (u16*)(w + off); off += 256 * 256 * 2;
  u16* wkvT = (u16*)(w + off); off += 512 * 256 * 2;
  u16* woT = (u16*)(w + off); off += 256 * 256 * 2;
  float* wtloT = (float*)(w + off); off += 256 * 256 * 4;
  float* btlo = (float*)(w + off); off += 256 * 4;
  float* bkv = (float*)(w + off); off += 512 * 4;
  u16* B5 = (u16*)(w + off); off += (size_t)16 * 256 * 512 * 2;  // 4MB
  if (ws_size < off) return;

  prep0<<<256, 256, 0, stream>>>(Wq, Wk, Wv, Wo, bk, bv, wqT, wkvT, woT, bkv);
  prep1<<<256, 256, 0, stream>>>(Wt, Wo, bt, bo, wtloT, btlo);

  // G1: q = x_q @ Wq + bq -> q_ws (bf16), N=256 (NT=2)
  gemm2<true, 4, false, false, 2><<<1024, 256, 0, stream>>>(
      x_q, nullptr, nullptr, wqT, 256, 0L, bq, q_ws, nullptr, nullptr);
  score_k<false><<<256, 256, 0, stream>>>(q_ws, 256, nullptr, Wqa, bqa, qscore);
  pool_k<<<128, 256, 0, stream>>>(qscore, q_ws, 256, pq);

  // G2: [k|v] = x_kv @ [Wk|Wv] + [bk|bv] -> k_ws, v_ws (N=512, NT=4)
  gemm2<true, 4, false, false, 4><<<2048, 256, 0, stream>>>(
      x_kv, nullptr, nullptr, wkvT, 256, 0L, bkv, k_ws, v_ws, nullptr);
  score_k<true><<<256, 256, 0, stream>>>(k_ws, 256, pq, Wka, bka, kscore);
  pool_k<<<128, 256, 0, stream>>>(kscore, k_ws, 256, pk);

  // per-n B5 = [diag(pk)*Wtlo ; Wo]  ([n][j][512])
  prep2<<<16 * 256, 256, 0, stream>>>(pk, wtloT, woT, B5);

  // G3: out = v @ B5_lo + q @ Wo + btlo  (dual-A, K=512, fp32 out, NT=2)
  gemm2<false, 8, true, true, 2><<<1024, 256, 0, stream>>>(
      nullptr, v_ws, q_ws, B5, 512, 131072L, btlo, nullptr, nullptr, (float*)d_out);
}